// Round 1
// baseline (56134.009 us; speedup 1.0000x reference)
//
#include <hip/hip_runtime.h>
#include <math.h>

#define T_STEPS 1024
#define NB 128
#define D_IN 512
#define D_H 1024
#define K_TOT (D_IN + D_H)   // 1536

#define JT 16     // output columns (d_h) per block
#define BT 32     // batch rows per block
#define CHUNK 128 // K chunk staged in LDS
#define LPAD 132  // padded LDS row stride (floats): 16B-aligned rows, conflict-free

#define FMA4(acc, xv, wv)                 \
    acc = fmaf((xv).x, (wv).x, acc);      \
    acc = fmaf((xv).y, (wv).y, acc);      \
    acc = fmaf((xv).z, (wv).z, acc);      \
    acc = fmaf((xv).w, (wv).w, acc);

__global__ __launch_bounds__(256) void rwa_init(float* __restrict__ nbuf,
                                                float* __restrict__ dbuf) {
    int i = blockIdx.x * 256 + threadIdx.x;
    if (i < NB * D_H) { nbuf[i] = 0.0f; dbuf[i] = 0.0f; }
}

__global__ __launch_bounds__(256) void rwa_step(
    const float* __restrict__ x,        // [T, NB, D_IN]
    const float* __restrict__ init_st,  // [D_H]
    const float* __restrict__ uW,       // [D_H, D_IN]
    const float* __restrict__ ub,       // [D_H]
    const float* __restrict__ gW,       // [D_H, K_TOT]
    const float* __restrict__ gb,       // [D_H]
    const float* __restrict__ aW,       // [D_H, K_TOT]
    float* __restrict__ out,            // [T, NB, D_H] ++ [NB, D_H]
    float* __restrict__ nbuf,
    float* __restrict__ dbuf,
    int t)
{
    __shared__ __align__(16) float xh[BT][LPAD];
    __shared__ __align__(16) float wu[JT][LPAD];
    __shared__ __align__(16) float wg[JT][LPAD];
    __shared__ __align__(16) float wa[JT][LPAD];

    const int tid = threadIdx.x;
    const int jl  = tid & (JT - 1);   // 0..15
    const int bp  = tid >> 4;         // 0..15 (pair of batch rows)
    const int j0  = blockIdx.x * JT;
    const int b0  = blockIdx.y * BT;

    // previous hidden state lives in the output buffer at step t-1
    const float* __restrict__ hprev =
        out + (size_t)(t > 0 ? t - 1 : 0) * NB * D_H;

    float au0 = 0.f, ag0 = 0.f, aa0 = 0.f;
    float au1 = 0.f, ag1 = 0.f, aa1 = 0.f;

    for (int k0 = 0; k0 < K_TOT; k0 += CHUNK) {
        const bool is_x = (k0 < D_IN);   // CHUNK divides D_IN, chunks never straddle

        // ---- stage xh tile [BT][CHUNK] (float4, coalesced)
        for (int l4 = tid; l4 < BT * (CHUNK / 4); l4 += 256) {
            const int r  = l4 >> 5;       // CHUNK/4 = 32 float4 per row
            const int c4 = l4 & 31;
            float4 v;
            if (is_x) {
                v = *(const float4*)&x[(size_t)t * NB * D_IN +
                                       (size_t)(b0 + r) * D_IN + k0 + c4 * 4];
            } else if (t > 0) {
                v = *(const float4*)&hprev[(size_t)(b0 + r) * D_H +
                                           (k0 - D_IN) + c4 * 4];
            } else {
                float4 iv = *(const float4*)&init_st[(k0 - D_IN) + c4 * 4];
                v.x = tanhf(iv.x); v.y = tanhf(iv.y);
                v.z = tanhf(iv.z); v.w = tanhf(iv.w);
            }
            *(float4*)&xh[r][c4 * 4] = v;
        }
        // ---- stage weight tiles [JT][CHUNK]
        for (int l4 = tid; l4 < JT * (CHUNK / 4); l4 += 256) {
            const int r  = l4 >> 5;
            const int c4 = l4 & 31;
            const int j  = j0 + r;
            const int kk = k0 + c4 * 4;
            *(float4*)&wg[r][c4 * 4] = *(const float4*)&gW[(size_t)j * K_TOT + kk];
            *(float4*)&wa[r][c4 * 4] = *(const float4*)&aW[(size_t)j * K_TOT + kk];
            if (is_x)
                *(float4*)&wu[r][c4 * 4] = *(const float4*)&uW[(size_t)j * D_IN + kk];
        }
        __syncthreads();

        const int bl0 = bp * 2, bl1 = bl0 + 1;
        if (is_x) {
            #pragma unroll 4
            for (int ki = 0; ki < CHUNK; ki += 4) {
                float4 x0  = *(const float4*)&xh[bl0][ki];
                float4 x1  = *(const float4*)&xh[bl1][ki];
                float4 wuv = *(const float4*)&wu[jl][ki];
                float4 wgv = *(const float4*)&wg[jl][ki];
                float4 wav = *(const float4*)&wa[jl][ki];
                FMA4(au0, x0, wuv); FMA4(au1, x1, wuv);
                FMA4(ag0, x0, wgv); FMA4(ag1, x1, wgv);
                FMA4(aa0, x0, wav); FMA4(aa1, x1, wav);
            }
        } else {
            #pragma unroll 4
            for (int ki = 0; ki < CHUNK; ki += 4) {
                float4 x0  = *(const float4*)&xh[bl0][ki];
                float4 x1  = *(const float4*)&xh[bl1][ki];
                float4 wgv = *(const float4*)&wg[jl][ki];
                float4 wav = *(const float4*)&wa[jl][ki];
                FMA4(ag0, x0, wgv); FMA4(ag1, x1, wgv);
                FMA4(aa0, x0, wav); FMA4(aa1, x1, wav);
            }
        }
        __syncthreads();
    }

    // ---- epilogue: nonlinear update for the two (b, j) outputs
    const int j   = j0 + jl;
    const float ubj = ub[j];
    const float gbj = gb[j];

    {
        const int b = b0 + bp * 2;
        float u = au0 + ubj;
        float g = ag0 + gbj;
        float z = u * tanhf(g);
        float ea = expf(aa0);
        size_t idx = (size_t)b * D_H + j;
        float nn = nbuf[idx] + z * ea;
        float dd = dbuf[idx] + ea;
        nbuf[idx] = nn; dbuf[idx] = dd;
        float ht = tanhf(nn / dd);
        out[(size_t)t * NB * D_H + idx] = ht;
        if (t == T_STEPS - 1) out[(size_t)T_STEPS * NB * D_H + idx] = ht;
    }
    {
        const int b = b0 + bp * 2 + 1;
        float u = au1 + ubj;
        float g = ag1 + gbj;
        float z = u * tanhf(g);
        float ea = expf(aa1);
        size_t idx = (size_t)b * D_H + j;
        float nn = nbuf[idx] + z * ea;
        float dd = dbuf[idx] + ea;
        nbuf[idx] = nn; dbuf[idx] = dd;
        float ht = tanhf(nn / dd);
        out[(size_t)t * NB * D_H + idx] = ht;
        if (t == T_STEPS - 1) out[(size_t)T_STEPS * NB * D_H + idx] = ht;
    }
}

extern "C" void kernel_launch(void* const* d_in, const int* in_sizes, int n_in,
                              void* d_out, int out_size, void* d_ws, size_t ws_size,
                              hipStream_t stream) {
    const float* x       = (const float*)d_in[0];
    const float* init_st = (const float*)d_in[1];
    const float* uW      = (const float*)d_in[2];
    const float* ub      = (const float*)d_in[3];
    const float* gW      = (const float*)d_in[4];
    const float* gb      = (const float*)d_in[5];
    const float* aW      = (const float*)d_in[6];
    float* out  = (float*)d_out;
    float* nbuf = (float*)d_ws;
    float* dbuf = nbuf + (size_t)NB * D_H;

    rwa_init<<<(NB * D_H + 255) / 256, 256, 0, stream>>>(nbuf, dbuf);

    dim3 grid(D_H / JT, NB / BT);  // (64, 4)
    for (int t = 0; t < T_STEPS; ++t) {
        rwa_step<<<grid, 256, 0, stream>>>(x, init_st, uW, ub, gW, gb, aW,
                                           out, nbuf, dbuf, t);
    }
}

// Round 2
// 31085.641 us; speedup vs baseline: 1.8058x; 1.8058x over previous
//
#include <hip/hip_runtime.h>
#include <math.h>

#define T_STEPS 1024
#define NB 128
#define D_IN 512
#define D_H 1024
#define K_TOT 1536
#define N_A 3072   // packed rows: [0,1024)=uW, [1024,2048)=gW_x, [2048,3072)=aW_x
#define N_H 2048   // packed rows, 16-interleaved: group g covers j in [16g,16g+16): 16 g-rows then 16 a-rows

typedef __bf16 bf16x8 __attribute__((ext_vector_type(8)));
typedef float f32x4 __attribute__((ext_vector_type(4)));

__device__ __forceinline__ unsigned short f2bf(float f) {
    unsigned int u = __float_as_uint(f);
    unsigned int r = 0x7fffu + ((u >> 16) & 1u);
    return (unsigned short)((u + r) >> 16);
}

// ---------------- one-time packing / init ----------------

__global__ __launch_bounds__(256) void pack_wa(
    const float* __restrict__ uW, const float* __restrict__ gW,
    const float* __restrict__ aW, unsigned short* __restrict__ wa) {
    int i = blockIdx.x * 256 + threadIdx.x;          // N_A * D_IN
    if (i >= N_A * D_IN) return;
    int rr = i >> 9, k = i & 511;
    float v;
    if (rr < 1024)       v = uW[(size_t)rr * D_IN + k];
    else if (rr < 2048)  v = gW[(size_t)(rr - 1024) * K_TOT + k];
    else                 v = aW[(size_t)(rr - 2048) * K_TOT + k];
    wa[i] = f2bf(v);
}

__global__ __launch_bounds__(256) void pack_wh(
    const float* __restrict__ gW, const float* __restrict__ aW,
    unsigned short* __restrict__ wh) {
    int i = blockIdx.x * 256 + threadIdx.x;          // N_H * D_H
    if (i >= N_H * D_H) return;
    int rr = i >> 10, k = i & 1023;
    int g = rr >> 5, ii = rr & 31, j = g * 16 + (ii & 15);
    const float* src = (ii < 16) ? gW : aW;
    wh[i] = f2bf(src[(size_t)j * K_TOT + D_IN + k]);
}

__global__ __launch_bounds__(256) void rwa_init(
    const float* __restrict__ init_st, float* __restrict__ nbuf,
    float* __restrict__ dbuf, unsigned short* __restrict__ h0) {
    int i = blockIdx.x * 256 + threadIdx.x;          // NB * D_H
    if (i >= NB * D_H) return;
    nbuf[i] = 0.f; dbuf[i] = 0.f;
    h0[i] = f2bf(tanhf(init_st[i & (D_H - 1)]));
}

// ---------------- phase A: pre = x_chunk @ W_A^T + bias ----------------
// x_chunk: [CT*128, 512] f32; wa: [3072, 512] bf16; pre: [CT*128, 3072] f32
// block tile 128x128, 4 waves (2x2), wave tile 64x64, K-chunk 64

__global__ __launch_bounds__(256) void phase_a(
    const float* __restrict__ x, const unsigned short* __restrict__ wa,
    const float* __restrict__ ub, const float* __restrict__ gb,
    float* __restrict__ pre)
{
    __shared__ unsigned short As[128][72];
    __shared__ unsigned short Bs[128][72];
    const int tid = threadIdx.x;
    const int bn = blockIdx.x;           // 0..23
    const int bm = blockIdx.y;           // 0..CT-1
    const int wave = tid >> 6, lane = tid & 63;
    const int wm = wave >> 1, wn = wave & 1;
    const int lr = lane & 15, lk = lane >> 4;

    f32x4 acc[4][4] = {};

    for (int k0 = 0; k0 < D_IN; k0 += 64) {
        for (int i = tid; i < 128 * 16; i += 256) {       // A: f32->bf16, float4 each
            int r = i >> 4, c4 = (i & 15) * 4;
            float4 v = *(const float4*)&x[(size_t)(bm * 128 + r) * D_IN + k0 + c4];
            unsigned short* d = &As[r][c4];
            d[0] = f2bf(v.x); d[1] = f2bf(v.y); d[2] = f2bf(v.z); d[3] = f2bf(v.w);
        }
        for (int i = tid; i < 128 * 8; i += 256) {        // B: 8 bf16 (16B) each
            int r = i >> 3, c8 = (i & 7) * 8;
            *(uint4*)&Bs[r][c8] =
                *(const uint4*)&wa[(size_t)(bn * 128 + r) * D_IN + k0 + c8];
        }
        __syncthreads();
        #pragma unroll
        for (int ks = 0; ks < 2; ++ks) {
            bf16x8 af[4], bfr[4];
            #pragma unroll
            for (int mf = 0; mf < 4; ++mf)
                af[mf] = *(const bf16x8*)&As[wm * 64 + mf * 16 + lr][ks * 32 + lk * 8];
            #pragma unroll
            for (int nf = 0; nf < 4; ++nf)
                bfr[nf] = *(const bf16x8*)&Bs[wn * 64 + nf * 16 + lr][ks * 32 + lk * 8];
            #pragma unroll
            for (int mf = 0; mf < 4; ++mf)
                #pragma unroll
                for (int nf = 0; nf < 4; ++nf)
                    acc[mf][nf] = __builtin_amdgcn_mfma_f32_16x16x32_bf16(
                        af[mf], bfr[nf], acc[mf][nf], 0, 0, 0);
        }
        __syncthreads();
    }

    #pragma unroll
    for (int nf = 0; nf < 4; ++nf) {
        int n = bn * 128 + wn * 64 + nf * 16 + lr;
        float bias = (n < 1024) ? ub[n] : ((n < 2048) ? gb[n - 1024] : 0.f);
        #pragma unroll
        for (int mf = 0; mf < 4; ++mf) {
            int mbase = bm * 128 + wm * 64 + mf * 16 + lk * 4;
            #pragma unroll
            for (int r = 0; r < 4; ++r)
                pre[(size_t)(mbase + r) * N_A + n] = acc[mf][nf][r] + bias;
        }
    }
}

// ---------------- step: C2 = h_prev @ W_H^T, fused nonlinear update ----------------
// grid (32, 2): bn over N=2048/64, bm over M=128/64. 4 waves (2x2), wave 32x32.

__global__ __launch_bounds__(256) void rwa_step(
    const unsigned short* __restrict__ hin,   // [128][1024] bf16
    unsigned short* __restrict__ hout,        // [128][1024] bf16
    const unsigned short* __restrict__ wh,    // [2048][1024] bf16
    const float* __restrict__ pre,            // [CT*128][3072] f32
    float* __restrict__ nbuf, float* __restrict__ dbuf,
    float* __restrict__ out, int t, int tc)
{
    __shared__ unsigned short As[64][136];
    __shared__ unsigned short Bs[64][136];
    const int tid = threadIdx.x;
    const int bn = blockIdx.x;   // 0..31
    const int bm = blockIdx.y;   // 0..1
    const int wave = tid >> 6, lane = tid & 63;
    const int wm = wave >> 1, wn = wave & 1;
    const int lr = lane & 15, lk = lane >> 4;

    f32x4 acc[2][2] = {};

    for (int k0 = 0; k0 < D_H; k0 += 128) {
        for (int i = tid; i < 64 * 16; i += 256) {
            int r = i >> 4, c8 = (i & 15) * 8;
            *(uint4*)&As[r][c8] =
                *(const uint4*)&hin[(size_t)(bm * 64 + r) * D_H + k0 + c8];
        }
        for (int i = tid; i < 64 * 16; i += 256) {
            int r = i >> 4, c8 = (i & 15) * 8;
            *(uint4*)&Bs[r][c8] =
                *(const uint4*)&wh[(size_t)(bn * 64 + r) * D_H + k0 + c8];
        }
        __syncthreads();
        #pragma unroll
        for (int ks = 0; ks < 4; ++ks) {
            bf16x8 af[2], bfr[2];
            #pragma unroll
            for (int mf = 0; mf < 2; ++mf)
                af[mf] = *(const bf16x8*)&As[wm * 32 + mf * 16 + lr][ks * 32 + lk * 8];
            #pragma unroll
            for (int nf = 0; nf < 2; ++nf)
                bfr[nf] = *(const bf16x8*)&Bs[wn * 32 + nf * 16 + lr][ks * 32 + lk * 8];
            #pragma unroll
            for (int mf = 0; mf < 2; ++mf)
                #pragma unroll
                for (int nf = 0; nf < 2; ++nf)
                    acc[mf][nf] = __builtin_amdgcn_mfma_f32_16x16x32_bf16(
                        af[mf], bfr[nf], acc[mf][nf], 0, 0, 0);
        }
        __syncthreads();
    }

    // epilogue: acc[mf][0] = g_h, acc[mf][1] = a_h for j-group (bn*2 + wn)
    const int grp = bn * 2 + wn;
    const int j = grp * 16 + lr;
    #pragma unroll
    for (int mf = 0; mf < 2; ++mf) {
        #pragma unroll
        for (int r = 0; r < 4; ++r) {
            int b = bm * 64 + wm * 32 + mf * 16 + lk * 4 + r;
            size_t prow = (size_t)(tc * 128 + b) * N_A;
            float u  = pre[prow + j];
            float gx = pre[prow + 1024 + j];
            float ax = pre[prow + 2048 + j];
            float g = gx + acc[mf][0][r];
            float a = ax + acc[mf][1][r];
            float ea = expf(a);
            float z = u * tanhf(g);
            size_t idx = (size_t)b * D_H + j;
            float nn = nbuf[idx] + z * ea;
            float dd = dbuf[idx] + ea;
            nbuf[idx] = nn; dbuf[idx] = dd;
            float h = tanhf(nn / dd);
            out[(size_t)t * NB * D_H + idx] = h;
            hout[idx] = f2bf(h);
            if (t == T_STEPS - 1) out[(size_t)T_STEPS * NB * D_H + idx] = h;
        }
    }
}

// ---------------- launch ----------------

extern "C" void kernel_launch(void* const* d_in, const int* in_sizes, int n_in,
                              void* d_out, int out_size, void* d_ws, size_t ws_size,
                              hipStream_t stream) {
    const float* x       = (const float*)d_in[0];
    const float* init_st = (const float*)d_in[1];
    const float* uW      = (const float*)d_in[2];
    const float* ub      = (const float*)d_in[3];
    const float* gW      = (const float*)d_in[4];
    const float* gb      = (const float*)d_in[5];
    const float* aW      = (const float*)d_in[6];
    float* out = (float*)d_out;

    char* ws = (char*)d_ws;
    float* nbuf = (float*)ws;                                   ws += (size_t)NB * D_H * 4;
    float* dbuf = (float*)ws;                                   ws += (size_t)NB * D_H * 4;
    unsigned short* hbf0 = (unsigned short*)ws;                 ws += (size_t)NB * D_H * 2;
    unsigned short* hbf1 = (unsigned short*)ws;                 ws += (size_t)NB * D_H * 2;
    unsigned short* wa = (unsigned short*)ws;                   ws += (size_t)N_A * D_IN * 2;
    unsigned short* wh = (unsigned short*)ws;                   ws += (size_t)N_H * D_H * 2;
    float* pre = (float*)ws;
    size_t fixed = (size_t)(ws - (char*)d_ws);
    size_t per_ct = (size_t)128 * N_A * 4;                      // 1.5 MB per step slot

    int CT = 1024;
    while (CT > 1 && fixed + (size_t)CT * per_ct > ws_size) CT >>= 1;

    pack_wa<<<(N_A * D_IN + 255) / 256, 256, 0, stream>>>(uW, gW, aW, wa);
    pack_wh<<<(N_H * D_H + 255) / 256, 256, 0, stream>>>(gW, aW, wh);
    rwa_init<<<(NB * D_H + 255) / 256, 256, 0, stream>>>(init_st, nbuf, dbuf, hbf0);

    for (int c = 0; c < T_STEPS / CT; ++c) {
        phase_a<<<dim3(24, CT), 256, 0, stream>>>(
            x + (size_t)c * CT * NB * D_IN, wa, ub, gb, pre);
        for (int tl = 0; tl < CT; ++tl) {
            int t = c * CT + tl;
            const unsigned short* hin = (t & 1) ? hbf1 : hbf0;
            unsigned short* hout      = (t & 1) ? hbf0 : hbf1;
            rwa_step<<<dim3(32, 2), 256, 0, stream>>>(
                hin, hout, wh, pre, nbuf, dbuf, out, t, tl);
        }
    }
}

// Round 3
// 12602.156 us; speedup vs baseline: 4.4543x; 2.4667x over previous
//
#include <hip/hip_runtime.h>
#include <math.h>

#define T_STEPS 1024
#define NB 128
#define D_IN 512
#define D_H 1024
#define K_TOT 1536
#define N_A 3072   // packed rows: [0,1024)=uW, [1024,2048)=gW_x, [2048,3072)=aW_x
#define N_H 2048   // packed rows: group g (j in [16g,16g+16)): 16 g-rows then 16 a-rows

typedef __bf16 bf16x8 __attribute__((ext_vector_type(8)));
typedef float f32x4 __attribute__((ext_vector_type(4)));

__device__ __forceinline__ unsigned short f2bf(float f) {
    unsigned int u = __float_as_uint(f);
    unsigned int r = 0x7fffu + ((u >> 16) & 1u);
    return (unsigned short)((u + r) >> 16);
}
__device__ __forceinline__ float bf2f(unsigned short v) {
    return __uint_as_float(((unsigned int)v) << 16);
}
__device__ __forceinline__ float fast_tanh(float x) {
    float ax = fabsf(x);
    float e = __expf(2.0f * ax);
    float t = 1.0f - 2.0f / (e + 1.0f);
    return copysignf(t, x);
}

// ---------------- one-time packing / init ----------------

__global__ __launch_bounds__(256) void pack_wa(
    const float* __restrict__ uW, const float* __restrict__ gW,
    const float* __restrict__ aW, unsigned short* __restrict__ wa) {
    int i = blockIdx.x * 256 + threadIdx.x;          // N_A * D_IN
    if (i >= N_A * D_IN) return;
    int rr = i >> 9, k = i & 511;
    float v;
    if (rr < 1024)       v = uW[(size_t)rr * D_IN + k];
    else if (rr < 2048)  v = gW[(size_t)(rr - 1024) * K_TOT + k];
    else                 v = aW[(size_t)(rr - 2048) * K_TOT + k];
    wa[i] = f2bf(v);
}

__global__ __launch_bounds__(256) void pack_wh(
    const float* __restrict__ gW, const float* __restrict__ aW,
    unsigned short* __restrict__ wh) {
    int i = blockIdx.x * 256 + threadIdx.x;          // N_H * D_H
    if (i >= N_H * D_H) return;
    int rr = i >> 10, k = i & 1023;
    int g = rr >> 5, ii = rr & 31, j = g * 16 + (ii & 15);
    const float* src = (ii < 16) ? gW : aW;
    wh[i] = f2bf(src[(size_t)j * K_TOT + D_IN + k]);
}

__global__ __launch_bounds__(256) void rwa_init(
    const float* __restrict__ init_st, float* __restrict__ nbuf,
    float* __restrict__ dbuf, unsigned short* __restrict__ h0) {
    int i = blockIdx.x * 256 + threadIdx.x;          // NB * D_H
    if (i >= NB * D_H) return;
    nbuf[i] = 0.f; dbuf[i] = 0.f;
    h0[i] = f2bf(tanhf(init_st[i & (D_H - 1)]));
}

// ---------------- phase A: pre = bf16( x_chunk @ W_A^T + bias ) ----------------
// x_chunk: [CT*128, 512] f32; wa: [3072, 512] bf16; pre: [CT*128, 3072] bf16

__global__ __launch_bounds__(256) void phase_a(
    const float* __restrict__ x, const unsigned short* __restrict__ wa,
    const float* __restrict__ ub, const float* __restrict__ gb,
    unsigned short* __restrict__ pre)
{
    __shared__ unsigned short As[128][72];
    __shared__ unsigned short Bs[128][72];
    const int tid = threadIdx.x;
    const int bn = blockIdx.x;           // 0..23
    const int bm = blockIdx.y;           // 0..CT-1
    const int wave = tid >> 6, lane = tid & 63;
    const int wm = wave >> 1, wn = wave & 1;
    const int lr = lane & 15, lk = lane >> 4;

    f32x4 acc[4][4] = {};

    for (int k0 = 0; k0 < D_IN; k0 += 64) {
        for (int i = tid; i < 128 * 16; i += 256) {       // A: f32->bf16
            int r = i >> 4, c4 = (i & 15) * 4;
            float4 v = *(const float4*)&x[(size_t)(bm * 128 + r) * D_IN + k0 + c4];
            unsigned short* d = &As[r][c4];
            d[0] = f2bf(v.x); d[1] = f2bf(v.y); d[2] = f2bf(v.z); d[3] = f2bf(v.w);
        }
        for (int i = tid; i < 128 * 8; i += 256) {        // B: 16B each
            int r = i >> 3, c8 = (i & 7) * 8;
            *(uint4*)&Bs[r][c8] =
                *(const uint4*)&wa[(size_t)(bn * 128 + r) * D_IN + k0 + c8];
        }
        __syncthreads();
        #pragma unroll
        for (int ks = 0; ks < 2; ++ks) {
            bf16x8 af[4], bfr[4];
            #pragma unroll
            for (int mf = 0; mf < 4; ++mf)
                af[mf] = *(const bf16x8*)&As[wm * 64 + mf * 16 + lr][ks * 32 + lk * 8];
            #pragma unroll
            for (int nf = 0; nf < 4; ++nf)
                bfr[nf] = *(const bf16x8*)&Bs[wn * 64 + nf * 16 + lr][ks * 32 + lk * 8];
            #pragma unroll
            for (int mf = 0; mf < 4; ++mf)
                #pragma unroll
                for (int nf = 0; nf < 4; ++nf)
                    acc[mf][nf] = __builtin_amdgcn_mfma_f32_16x16x32_bf16(
                        af[mf], bfr[nf], acc[mf][nf], 0, 0, 0);
        }
        __syncthreads();
    }

    #pragma unroll
    for (int nf = 0; nf < 4; ++nf) {
        int n = bn * 128 + wn * 64 + nf * 16 + lr;
        float bias = (n < 1024) ? ub[n] : ((n < 2048) ? gb[n - 1024] : 0.f);
        #pragma unroll
        for (int mf = 0; mf < 4; ++mf) {
            int mbase = bm * 128 + wm * 64 + mf * 16 + lk * 4;
            #pragma unroll
            for (int r = 0; r < 4; ++r)
                pre[(size_t)(mbase + r) * N_A + n] = f2bf(acc[mf][nf][r] + bias);
        }
    }
}

// ---------------- step: gh/ah = h_prev @ W_H^T (fused update) ----------------
// grid (64, 4): bn = j-group of 16, bm = 32-row b-group. 512 threads = 8 waves:
// (wm in {0,1}) x (kq in [0,4)) — kq waves split K, LDS reduction at end.

__global__ __launch_bounds__(512) void rwa_step(
    const unsigned short* __restrict__ hin,   // [128][1024] bf16
    unsigned short* __restrict__ hout,        // [128][1024] bf16
    const unsigned short* __restrict__ wh,    // [2048][1024] bf16
    const unsigned short* __restrict__ pre,   // [CT*128][3072] bf16
    float* __restrict__ nbuf, float* __restrict__ dbuf,
    float* __restrict__ out, int t, int tc)
{
    __shared__ unsigned short As[32][512];   // 32 KB (h tile, K-half)
    __shared__ unsigned short Bs[32][512];   // 32 KB (wh tile, K-half)
    const int tid = threadIdx.x;
    const int bn = blockIdx.x;   // 0..63
    const int bm = blockIdx.y;   // 0..3
    const int wave = tid >> 6, lane = tid & 63;
    const int wm = wave >> 2;    // 0..1 : 16-row b-slice
    const int kq = wave & 3;     // 0..3 : K quarter (128 each per half... 128*? )
    const int lr = lane & 15, lk = lane >> 4;

    f32x4 accg = {}, acca = {};

    #pragma unroll
    for (int half = 0; half < 2; ++half) {
        const int kbase = half * 512;
        // stage A[32][512] + B[32][512], XOR-swizzled 16B granules
        for (int s = tid; s < 4096; s += 512) {
            int which = s >> 11;          // 0:A 1:B
            int seg = s & 2047;
            int r = seg >> 6;             // 0..31
            int g = seg & 63;             // 16B granule in row
            const unsigned short* src = which
                ? wh  + (size_t)(bn * 32 + r) * 1024 + kbase + g * 8
                : hin + (size_t)(bm * 32 + r) * 1024 + kbase + g * 8;
            uint4 v = *(const uint4*)src;
            int gs = g ^ (r & 7);
            if (which) *(uint4*)&Bs[r][gs * 8] = v;
            else       *(uint4*)&As[r][gs * 8] = v;
        }
        __syncthreads();
        // wave kq: ksteps kq*4 .. kq*4+4 within this half (k = 128 elems)
        #pragma unroll
        for (int ks = 0; ks < 4; ++ks) {
            const int k = (kq * 4 + ks) * 32 + lk * 8;     // elem in [0,512)
            const int gidx = k >> 3;
            const int ar = wm * 16 + lr;
            bf16x8 av = *(const bf16x8*)&As[ar][(gidx ^ (ar & 7)) << 3];
            bf16x8 bg = *(const bf16x8*)&Bs[lr][(gidx ^ (lr & 7)) << 3];
            bf16x8 ba = *(const bf16x8*)&Bs[16 + lr][(gidx ^ (lr & 7)) << 3];
            accg = __builtin_amdgcn_mfma_f32_16x16x32_bf16(av, bg, accg, 0, 0, 0);
            acca = __builtin_amdgcn_mfma_f32_16x16x32_bf16(av, ba, acca, 0, 0, 0);
        }
        __syncthreads();
    }

    // cross-wave K reduction through LDS (reuse As): slots [wm*3 + kq-1]
    float* scr = (float*)&As[0][0];
    if (kq != 0) {
        int base = (wm * 3 + (kq - 1)) * 512 + lane * 4;
        *(f32x4*)&scr[base]       = accg;
        *(f32x4*)&scr[base + 256] = acca;
    }
    __syncthreads();

    if (kq == 0) {
        #pragma unroll
        for (int s = 0; s < 3; ++s) {
            int base = (wm * 3 + s) * 512 + lane * 4;
            accg += *(const f32x4*)&scr[base];
            acca += *(const f32x4*)&scr[base + 256];
        }
        const int j = bn * 16 + lr;
        #pragma unroll
        for (int r = 0; r < 4; ++r) {
            int b = bm * 32 + wm * 16 + lk * 4 + r;
            size_t pb = (size_t)(tc * 128 + b) * N_A;
            float u  = bf2f(pre[pb + j]);
            float gx = bf2f(pre[pb + 1024 + j]);
            float ax = bf2f(pre[pb + 2048 + j]);
            float g = gx + accg[r];
            float a = ax + acca[r];
            float ea = __expf(a);
            float z = u * fast_tanh(g);
            size_t idx = (size_t)b * D_H + j;
            float nn = nbuf[idx] + z * ea;
            float dd = dbuf[idx] + ea;
            nbuf[idx] = nn; dbuf[idx] = dd;
            float h = fast_tanh(nn / dd);
            out[(size_t)t * NB * D_H + idx] = h;
            hout[idx] = f2bf(h);
            if (t == T_STEPS - 1) out[(size_t)T_STEPS * NB * D_H + idx] = h;
        }
    }
}

// ---------------- launch ----------------

extern "C" void kernel_launch(void* const* d_in, const int* in_sizes, int n_in,
                              void* d_out, int out_size, void* d_ws, size_t ws_size,
                              hipStream_t stream) {
    const float* x       = (const float*)d_in[0];
    const float* init_st = (const float*)d_in[1];
    const float* uW      = (const float*)d_in[2];
    const float* ub      = (const float*)d_in[3];
    const float* gW      = (const float*)d_in[4];
    const float* gb      = (const float*)d_in[5];
    const float* aW      = (const float*)d_in[6];
    float* out = (float*)d_out;

    char* ws = (char*)d_ws;
    float* nbuf = (float*)ws;                                   ws += (size_t)NB * D_H * 4;
    float* dbuf = (float*)ws;                                   ws += (size_t)NB * D_H * 4;
    unsigned short* hbf0 = (unsigned short*)ws;                 ws += (size_t)NB * D_H * 2;
    unsigned short* hbf1 = (unsigned short*)ws;                 ws += (size_t)NB * D_H * 2;
    unsigned short* wa = (unsigned short*)ws;                   ws += (size_t)N_A * D_IN * 2;
    unsigned short* wh = (unsigned short*)ws;                   ws += (size_t)N_H * D_H * 2;
    unsigned short* pre = (unsigned short*)ws;
    size_t fixed = (size_t)(ws - (char*)d_ws);
    size_t per_ct = (size_t)128 * N_A * 2;                      // 768 KB per step slot

    int CT = 1024;
    while (CT > 1 && fixed + (size_t)CT * per_ct > ws_size) CT >>= 1;

    pack_wa<<<(N_A * D_IN + 255) / 256, 256, 0, stream>>>(uW, gW, aW, wa);
    pack_wh<<<(N_H * D_H + 255) / 256, 256, 0, stream>>>(gW, aW, wh);
    rwa_init<<<(NB * D_H + 255) / 256, 256, 0, stream>>>(init_st, nbuf, dbuf, hbf0);

    for (int c = 0; c < T_STEPS / CT; ++c) {
        phase_a<<<dim3(24, CT), 256, 0, stream>>>(
            x + (size_t)c * CT * NB * D_IN, wa, ub, gb, pre);
        for (int tl = 0; tl < CT; ++tl) {
            int t = c * CT + tl;
            const unsigned short* hin = (t & 1) ? hbf1 : hbf0;
            unsigned short* hout      = (t & 1) ? hbf0 : hbf1;
            rwa_step<<<dim3(64, 4), 512, 0, stream>>>(
                hin, hout, wh, pre, nbuf, dbuf, out, t, tl);
        }
    }
}